// Round 9
// baseline (127.082 us; speedup 1.0000x reference)
//
#include <hip/hip_runtime.h>
#include <hip/hip_bf16.h>
#include <utility>

// fUpModule CG tensor product, MAXL=5, TAUS=OUT_TAUS=8, BATCH=1024, fp32 I/O.
// R9: R4 config (1024 blocks, 36KB LDS, 9 chunks) + single kernel (std via
// v_rcp) + PACKED fp32 math: complex re/im pairs as ext_vector_type(2) float
// with __builtin_elementwise_fma -> v_pk_fma_f32 (2x fp32 rate, ~half the
// instruction bytes). Stage 1: 3 pk ops/term via precomputed <-cy,cx>.
// Stage 2: 2 output channels/wave, shared swapped mid operand.

typedef float v2f __attribute__((ext_vector_type(2)));

constexpr int NTRIP = 69;
constexpr int NL    = 6;
constexpr int BATCH = 1024;
constexpr int ROW   = 288;     // complex elements per activation/output row
constexpr int MID_LDS = 4224;  // v2f slots for mid buffer (33 KB)
constexpr int MAXIT = 64;
constexpr int MAXCH = 3;

struct Meta {
    int tl1[NTRIP], tl2[NTRIP], tll[NTRIP];
    int tf1[NTRIP], tf2[NTRIP];
    int ttloc[NTRIP];
    int trip_of_l[NL][16];
    int ntrips[NL];
    int mid_tau[NL], std_off[NL], w_off[NL], f_l[NL];
    int nch[NL];
    int ch_start[NL][MAXCH], ch_cnt[NL][MAXCH];
    int nit[NL];
    int it_slot[NL][MAXIT], it_m0[NL][MAXIT], it_m1[NL][MAXIT];
    int it_wave[NL][MAXIT], it_ch[NL][MAXIT];
};

constexpr int win_lo(int l1, int l2, int l, int mi) {
    int v = mi - l + l1 - l2; return v < 0 ? 0 : v;
}
constexpr int win_hi(int l1, int l2, int l, int mi) {
    int v = mi - l + l1 + l2; return v > 2 * l1 ? 2 * l1 : v;
}

constexpr Meta build_meta() {
    Meta m{};
    int fl[NL] = {};
    {
        int acc = 0;
        for (int l = 0; l < NL; l++) { fl[l] = acc; m.f_l[l] = acc; acc += 8 * (2 * l + 1); }
    }
    int idx = 0;
    for (int l1 = 0; l1 <= 5; l1++)
        for (int l2 = 0; l2 <= l1; l2++) {
            int lmax = (l1 + l2 < 5) ? (l1 + l2) : 5;
            for (int l = l1 - l2; l <= lmax; l++) {
                m.tl1[idx] = l1; m.tl2[idx] = l2; m.tll[idx] = l;
                m.tf1[idx] = fl[l1]; m.tf2[idx] = fl[l2];
                m.ttloc[idx] = 64 * m.ntrips[l];
                m.trip_of_l[l][m.ntrips[l]] = idx;
                m.ntrips[l]++;
                idx++;
            }
        }
    int so = 0, wo = 0;
    for (int l = 0; l < NL; l++) {
        m.mid_tau[l] = 64 * m.ntrips[l];
        m.std_off[l] = so; so += m.mid_tau[l];
        m.w_off[l]   = wo; wo += 8 * m.mid_tau[l];
    }
    for (int l = 0; l < NL; l++) {
        const int TW = 2 * l + 1;
        const int maxslot = MID_LDS / (64 * TW);
        const int ntl = m.ntrips[l];
        const int nch = (ntl + maxslot - 1) / maxslot;
        m.nch[l] = nch;
        if (nch > MAXCH) return Meta{};   // poison -> static_asserts fire
        int done = 0;
        for (int c = 0; c < nch; c++) {
            int cnt = (ntl - done + (nch - c) - 1) / (nch - c);
            m.ch_start[l][c] = done; m.ch_cnt[l][c] = cnt; done += cnt;
        }
        // items: l<=2 whole slots; l>=3 split into 2 m-ranges
        const int npmax = (l <= 2) ? 1 : 2;
        int nit = 0;
        for (int c = 0; c < nch; c++) {
            const int it_first = nit;
            for (int si = m.ch_start[l][c]; si < m.ch_start[l][c] + m.ch_cnt[l][c]; si++) {
                int trip = m.trip_of_l[l][si];
                int l1 = m.tl1[trip], l2 = m.tl2[trip];
                int wm[16] = {}; int tot = 0;
                for (int mi = 0; mi < TW; mi++) {
                    wm[mi] = win_hi(l1, l2, l, mi) - win_lo(l1, l2, l, mi) + 1;
                    tot += wm[mi];
                }
                int np = npmax;
                if (np > TW) np = TW;
                int mcur = 0, acc2 = 0;
                for (int p = 0; p < np; p++) {
                    int target = (tot * (p + 1)) / np;
                    int m0 = mcur;
                    while (mcur < TW - (np - 1 - p) && (acc2 < target || mcur == m0)) {
                        acc2 += wm[mcur]; mcur++;
                    }
                    if (nit >= MAXIT) return Meta{};
                    m.it_slot[l][nit] = si;
                    m.it_m0[l][nit] = m0;
                    m.it_m1[l][nit] = mcur - 1;
                    m.it_ch[l][nit] = c;
                    nit++;
                }
            }
            // greedy cost-balanced assignment of this chunk's items to 4 waves
            int cost[MAXIT] = {}; bool asg[MAXIT] = {};
            for (int i = it_first; i < nit; i++) {
                int trip = m.trip_of_l[l][m.it_slot[l][i]];
                int l1 = m.tl1[trip], l2 = m.tl2[trip];
                int tc = 0;
                for (int mi = m.it_m0[l][i]; mi <= m.it_m1[l][i]; mi++)
                    tc += win_hi(l1, l2, l, mi) - win_lo(l1, l2, l, mi) + 1;
                cost[i] = tc * 3 + (2 * l1 + 2 * l2 + 2) * 2;
            }
            int load[4] = {};
            for (int k = it_first; k < nit; k++) {
                int best = -1, bc = -1;
                for (int i = it_first; i < nit; i++)
                    if (!asg[i] && cost[i] > bc) { bc = cost[i]; best = i; }
                asg[best] = true;
                int wsel = 0;
                for (int w2 = 1; w2 < 4; w2++) if (load[w2] < load[wsel]) wsel = w2;
                m.it_wave[l][best] = wsel;
                load[wsel] += bc;
            }
        }
        m.nit[l] = nit;
    }
    return m;
}

constexpr Meta MT = build_meta();
constexpr int WLEN = 35328;
static_assert(MT.w_off[5] + 8 * MT.mid_tau[5] == WLEN, "wlen (meta poisoned?)");
static_assert(MT.std_off[5] + MT.mid_tau[5] == 4416, "stdlen");
static_assert(MT.nch[4] <= MAXCH && MT.nch[5] <= MAXCH, "nch");

// ---------------------------------------------------- constexpr CG coeffs ---
constexpr double cfact(int n) {
    double r = 1.0;
    for (int i = 2; i <= n; i++) r *= (double)i;
    return r;
}
constexpr double csqrt(double x) {
    double g = x > 1.0 ? x : 1.0;
    for (int i = 0; i < 100; i++) g = 0.5 * (g + x / g);
    return g;
}
constexpr float cg_coeff(int l1, int l2, int l, int m1, int m2, int m) {
    if (m1 + m2 != m) return 0.0f;
    double pre = csqrt((double)(2 * l + 1) * cfact(l + l1 - l2) * cfact(l - l1 + l2) *
                       cfact(l1 + l2 - l) / cfact(l1 + l2 + l + 1));
    pre *= csqrt(cfact(l + m) * cfact(l - m) * cfact(l1 - m1) * cfact(l1 + m1) *
                 cfact(l2 - m2) * cfact(l2 + m2));
    double s = 0.0;
    for (int k = 0; k <= l1 + l2 - l; k++) {
        int d0 = k, d1 = l1 + l2 - l - k, d2 = l1 - m1 - k;
        int d3 = l2 + m2 - k, d4 = l - l2 + m1 + k, d5 = l - l1 - m2 + k;
        if (d0 < 0 || d1 < 0 || d2 < 0 || d3 < 0 || d4 < 0 || d5 < 0) continue;
        double den = cfact(d0) * cfact(d1) * cfact(d2) * cfact(d3) * cfact(d4) * cfact(d5);
        s += ((k & 1) ? -1.0 : 1.0) / den;
    }
    return (float)(pre * s);
}

// per-item F row subranges (constexpr)
constexpr int rng_alo(int l1, int l2, int l, int m0, int m1) {
    int r = 2 * l1;
    for (int mi = m0; mi <= m1; mi++) { int v = win_lo(l1, l2, l, mi); if (v < r) r = v; }
    return r;
}
constexpr int rng_ahi(int l1, int l2, int l, int m0, int m1) {
    int r = 0;
    for (int mi = m0; mi <= m1; mi++) { int v = win_hi(l1, l2, l, mi); if (v > r) r = v; }
    return r;
}
constexpr int rng_clo(int l1, int l2, int l, int m0, int m1) {
    int r = 2 * l2;
    for (int mi = m0; mi <= m1; mi++) {
        int v = (mi - l) + l1 + l2 - win_hi(l1, l2, l, mi); if (v < r) r = v;
    }
    return r;
}
constexpr int rng_chi(int l1, int l2, int l, int m0, int m1) {
    int r = 0;
    for (int mi = m0; mi <= m1; mi++) {
        int v = (mi - l) + l1 + l2 - win_lo(l1, l2, l, mi); if (v > r) r = v;
    }
    return r;
}

// compile-time for
template <int... Is, class F>
__device__ __forceinline__ void static_for_impl(std::integer_sequence<int, Is...>, F&& f) {
    (f(std::integral_constant<int, Is>{}), ...);
}
template <int N, class F>
__device__ __forceinline__ void static_for(F&& f) {
    static_for_impl(std::make_integer_sequence<int, N>{}, (F&&)f);
}

__device__ __forceinline__ v2f pk_fma(v2f a, v2f b, v2f c) {
    return __builtin_elementwise_fma(a, b, c);
}
__device__ __forceinline__ v2f splat(float x) { v2f r; r.x = x; r.y = x; return r; }

// ------------------------------------------------------------- main kernel --
template <int L>
__device__ __forceinline__ void process_l(int b, int tid,
                                          const v2f* __restrict__ F,
                                          v2f* __restrict__ mid,
                                          const float2* __restrict__ wts,
                                          const float* __restrict__ stdv,
                                          float2* __restrict__ out) {
    constexpr int TW  = 2 * L + 1;
    constexpr int NCH = MT.nch[L];
    constexpr int NT  = MT.mid_tau[L];

    const int wid  = tid >> 6;     // wave 0..3
    const int lane = tid & 63;
    const int t = lane >> 3, s = lane & 7;

    v2f acc0[TW], acc1[TW];        // o = wid, o = wid + 4
#pragma unroll
    for (int i = 0; i < TW; i++) { acc0[i] = splat(0.f); acc1[i] = splat(0.f); }

    static_for<NCH>([&](auto CHc) {
        constexpr int CH  = decltype(CHc)::value;
        constexpr int S0  = MT.ch_start[L][CH];
        constexpr int CNT = MT.ch_cnt[L][CH];
        constexpr int CT  = CNT * 64;
        static_assert(CT * TW <= MID_LDS, "chunk fits");

        __syncthreads();   // previous consumers of `mid` done (covers F load too)

        // ---- stage 1: mid[m][T] via balanced (slot, m-range) items -------
        static_for<MT.nit[L]>([&](auto ITc) {
            constexpr int IT = decltype(ITc)::value;
            if constexpr (MT.it_ch[L][IT] == CH) {
                constexpr int SI   = MT.it_slot[L][IT];
                constexpr int TRIP = MT.trip_of_l[L][SI];
                constexpr int L1   = MT.tl1[TRIP];
                constexpr int L2v  = MT.tl2[TRIP];
                constexpr int N1   = 2 * L1 + 1, N2 = 2 * L2v + 1;
                constexpr int M0   = MT.it_m0[L][IT], M1 = MT.it_m1[L][IT];
                constexpr int ALO  = rng_alo(L1, L2v, L, M0, M1);
                constexpr int AHI  = rng_ahi(L1, L2v, L, M0, M1);
                constexpr int CLO  = rng_clo(L1, L2v, L, M0, M1);
                constexpr int CHI_ = rng_chi(L1, L2v, L, M0, M1);
                if (MT.it_wave[L][IT] == wid) {
                    const v2f* F1 = F + MT.tf1[TRIP] + t * N1;
                    const v2f* F2 = F + MT.tf2[TRIP] + s * N2;
                    v2f f1[AHI - ALO + 1], f2[CHI_ - CLO + 1], f2s[CHI_ - CLO + 1];
#pragma unroll
                    for (int i = 0; i <= AHI - ALO; i++) f1[i] = F1[ALO + i];
#pragma unroll
                    for (int i = 0; i <= CHI_ - CLO; i++) {
                        v2f c = F2[CLO + i];
                        f2[i] = c;
                        v2f cs; cs.x = -c.y; cs.y = c.x;   // <-cy, cx>
                        f2s[i] = cs;
                    }
                    const int Tloc = (MT.ttloc[TRIP] - S0 * 64) + lane;
                    static_for<M1 - M0 + 1>([&](auto MIc) {
                        constexpr int MI   = M0 + decltype(MIc)::value;
                        constexpr int BASE = MI - L;
                        constexpr int LO   = win_lo(L1, L2v, L, MI);
                        constexpr int HI   = win_hi(L1, L2v, L, MI);
                        v2f accv = splat(0.f);
                        static_for<HI - LO + 1>([&](auto Kc) {
                            constexpr int AI = LO + decltype(Kc)::value;
                            constexpr int CI = BASE + L1 + L2v - AI;
                            constexpr float cv = cg_coeff(L1, L2v, L, AI - L1, CI - L2v, BASE);
                            if constexpr (cv != 0.0f) {
                                const v2f a = f1[AI - ALO];
                                // inner = ax*<cx,cy> + ay*<-cy,cx>  (complex mul)
                                v2f inner = pk_fma(splat(a.x), f2[CI - CLO],
                                                   splat(a.y) * f2s[CI - CLO]);
                                accv = pk_fma(splat(cv), inner, accv);
                            }
                        });
                        mid[MI * CT + Tloc] = accv;
                    });
                }
            }
        });
        __syncthreads();

        // ---- stage 2: acc[o,m] += sum_T (W[o,T]/std[T])*mid[m][T] --------
        const float2* W0 = wts + MT.w_off[L] + wid * NT + S0 * 64;
        const float2* W1 = wts + MT.w_off[L] + (wid + 4) * NT + S0 * 64;
        const float*  Sb = stdv + MT.std_off[L] + S0 * 64;
        for (int T = lane * 2; T < CT; T += 128) {
            const float4 w0r = *reinterpret_cast<const float4*>(W0 + T);
            const float4 w1r = *reinterpret_cast<const float4*>(W1 + T);
            const float2 sd  = *reinterpret_cast<const float2*>(Sb + T);
            const float i0 = __builtin_amdgcn_rcpf(sd.x + 1e-5f);
            const float i1 = __builtin_amdgcn_rcpf(sd.y + 1e-5f);
            const v2f wx0a = splat(w0r.x * i0), wy0a = splat(w0r.y * i0);
            const v2f wx0b = splat(w0r.z * i1), wy0b = splat(w0r.w * i1);
            const v2f wx1a = splat(w1r.x * i0), wy1a = splat(w1r.y * i0);
            const v2f wx1b = splat(w1r.z * i1), wy1b = splat(w1r.w * i1);
#pragma unroll
            for (int mi = 0; mi < TW; mi++) {
                const float4 mv = *reinterpret_cast<const float4*>(mid + mi * CT + T);
                v2f m0; m0.x = mv.x; m0.y = mv.y;
                v2f m1; m1.x = mv.z; m1.y = mv.w;
                v2f m0s; m0s.x = -mv.y; m0s.y = mv.x;
                v2f m1s; m1s.x = -mv.w; m1s.y = mv.z;
                acc0[mi] = pk_fma(wx0a, m0, acc0[mi]);
                acc0[mi] = pk_fma(wy0a, m0s, acc0[mi]);
                acc0[mi] = pk_fma(wx0b, m1, acc0[mi]);
                acc0[mi] = pk_fma(wy0b, m1s, acc0[mi]);
                acc1[mi] = pk_fma(wx1a, m0, acc1[mi]);
                acc1[mi] = pk_fma(wy1a, m0s, acc1[mi]);
                acc1[mi] = pk_fma(wx1b, m1, acc1[mi]);
                acc1[mi] = pk_fma(wy1b, m1s, acc1[mi]);
            }
        }
    });

    // merge-reduce: lo half ends with sum for o=wid, hi half for o=wid+4
    const bool lo = (lane < 32);
    float2 red[TW];
#pragma unroll
    for (int mi = 0; mi < TW; mi++) {
        float gx = lo ? acc1[mi].x : acc0[mi].x;   // value to give away
        float gy = lo ? acc1[mi].y : acc0[mi].y;
        float rx = (lo ? acc0[mi].x : acc1[mi].x) + __shfl_xor(gx, 32, 64);
        float ry = (lo ? acc0[mi].y : acc1[mi].y) + __shfl_xor(gy, 32, 64);
#pragma unroll
        for (int off = 16; off >= 1; off >>= 1) {
            rx += __shfl_xor(rx, off, 64);
            ry += __shfl_xor(ry, off, 64);
        }
        red[mi] = make_float2(rx, ry);
    }
    if (lane == 0 || lane == 32) {
        const int o = wid + (lo ? 0 : 4);
        float2* orow = out + (size_t)b * ROW + MT.f_l[L] + o * TW;
#pragma unroll
        for (int mi = 0; mi < TW; mi++) orow[mi] = red[mi];
    }
}

__global__ __launch_bounds__(256, 4) void fup_main(const float2* __restrict__ act,
                                                   const float2* __restrict__ wts,
                                                   const float* __restrict__ stdv,
                                                   float2* __restrict__ out) {
    __shared__ v2f F[ROW];
    __shared__ __align__(16) v2f mid[MID_LDS];
    const int b = blockIdx.x;
    const int tid = threadIdx.x;
    const float2* arow = act + (size_t)b * ROW;
    for (int i = tid; i < ROW; i += 256) {
        float2 v = arow[i];
        v2f f; f.x = v.x; f.y = v.y;
        F[i] = f;
    }
    // sync happens at top of first chunk inside process_l<0>
    process_l<0>(b, tid, F, mid, wts, stdv, out);
    process_l<1>(b, tid, F, mid, wts, stdv, out);
    process_l<2>(b, tid, F, mid, wts, stdv, out);
    process_l<3>(b, tid, F, mid, wts, stdv, out);
    process_l<4>(b, tid, F, mid, wts, stdv, out);
    process_l<5>(b, tid, F, mid, wts, stdv, out);
}

// ----------------------------------------------------------------- launch ---
extern "C" void kernel_launch(void* const* d_in, const int* in_sizes, int n_in,
                              void* d_out, int out_size, void* d_ws, size_t ws_size,
                              hipStream_t stream) {
    const float2* act  = (const float2*)d_in[0];
    const float2* wts  = (const float2*)d_in[1];
    const float*  stdv = (const float*)d_in[2];
    float2* out = (float2*)d_out;

    hipLaunchKernelGGL(fup_main, dim3(BATCH), dim3(256), 0, stream,
                       act, wts, stdv, out);
}